// Round 7
// baseline (170.753 us; speedup 1.0000x reference)
//
#include <hip/hip_runtime.h>

// LIF SNN, 50 timesteps x 8192 neurons.
// 1) prep:         x f32 -> bf16 (padded to 64 t, vectorized), zero flag
// 2) ff_gemm_mfma: P[ks][t][j] = sum_{k in chunk} x[t][k]*w_in[j][k], bf16 MFMA.
//                  BARRIER-FREE per-wave LDS staging: each wave stages the 16
//                  W-rows only it consumes (2 rows x 512B contiguous per load
//                  instr, 4x bigger DRAM bursts than direct-to-fragment),
//                  cvt->bf16 -> XOR-swizzled LDS, double-buffered per wave.
//                  No __syncthreads in the whole kernel.
// 3) scan_fused:   reduce 8 bf16 partial planes -> ff[50] in regs -> LIF scan
//                  assuming no spikes (threshold margin ~15 units); writes out,
//                  FF (for fallback), flags if any spike occurred.
// 4) lif_fallback: exact sequential event-driven scan, runs only if flagged.

#define NEUR 8192
#define TSTEPS 50
#define TPAD 64
#define KSPLIT 8
#define KC (NEUR / KSPLIT)   // 1024
#define NTILE (KC / 128)     // 8 tiles of BK=128 floats

typedef __attribute__((ext_vector_type(8))) short bs8;           // 8 bf16
typedef __attribute__((ext_vector_type(4))) float fx4;           // MFMA C/D
typedef __attribute__((ext_vector_type(8))) unsigned short us8;  // 8 bf16 bits
typedef __attribute__((ext_vector_type(4))) unsigned short us4;  // 4 bf16 bits

static __device__ __forceinline__ unsigned short f2b(float f) {
    // f32 -> bf16 round-to-nearest-even
    unsigned u = __float_as_uint(f);
    return (unsigned short)((u + 0x7FFFu + ((u >> 16) & 1u)) >> 16);
}
static __device__ __forceinline__ float b2f(unsigned short b) {
    return __uint_as_float(((unsigned)b) << 16);
}

// ---------------- K0: convert x (vectorized), zero flag ----------------
__global__ __launch_bounds__(256)
void prep(const float* __restrict__ x, unsigned short* __restrict__ xb,
          int* __restrict__ flag)
{
    const int e8 = blockIdx.x * 256 + threadIdx.x;   // < TPAD*NEUR/8 = 65536
    const int e  = e8 * 8;
    const int t  = e >> 13;
    us8 o;
    if (t < TSTEPS) {
        const float4 lo = *(const float4*)&x[e];
        const float4 hi = *(const float4*)&x[e + 4];
        o = (us8){f2b(lo.x), f2b(lo.y), f2b(lo.z), f2b(lo.w),
                  f2b(hi.x), f2b(hi.y), f2b(hi.z), f2b(hi.w)};
    } else {
        o = (us8){0, 0, 0, 0, 0, 0, 0, 0};
    }
    *(us8*)&xb[e] = o;
    if (e8 == 0) *flag = 0;
}

// ---------------- K1: feed-forward GEMM, barrier-free LDS-staged ----------------
// grid = 128 j-blocks (64 j) x 8 k-splits = 1024 (all resident at 4/CU);
// block = 4 waves; wave wv stages AND computes rows j0+wv*16 .. +15.
__global__ __launch_bounds__(256, 4)   // cap <=128 VGPR: 4 blocks/CU
void ff_gemm_mfma(const float* __restrict__ w,            // [8192][8192]
                  const unsigned short* __restrict__ xb,  // [64][8192] bf16 bits
                  unsigned short* __restrict__ P)         // [KSPLIT][50][8192] bf16
{
    __shared__ __align__(16) unsigned char smem[2][64 * 256];  // 2 x 16 KB bf16

    const int tid  = threadIdx.x;
    const int wv   = tid >> 6;
    const int lane = tid & 63;
    const int jb   = blockIdx.x & 127;    // 128 j-blocks
    const int ks   = blockIdx.x >> 7;     // 8 k-splits
    const int j0   = jb * 64;
    const int k0   = ks * KC;
    const int lrow = lane & 15;           // fragment free-dim index
    const int lgrp = lane >> 4;           // k-group (0..3), 8 k each
    const int sr   = lane >> 5;           // stage: row parity (2 rows/instr)
    const int sc   = lane & 31;           // stage: 16B slot within 512B chunk
    const int wrow0 = wv * 16;            // this wave's private row window

    // stage source: rows j0+wrow0+sr + it*2, floats k0 + s*128 + sc*4 .. +4
    const float* const wst = w + (size_t)(j0 + wrow0 + sr) * NEUR + k0 + sc * 4;

    // A pointers (bf16 elements, L2-hot)
    const unsigned short* const xq0 = xb + (size_t)lrow * NEUR + k0 + lgrp * 8;
    const unsigned short* const xq1 = xq0 + (size_t)16 * NEUR;
    const unsigned short* const xq2 = xq0 + (size_t)32 * NEUR;
    const unsigned short* const xq3 = xq0 + (size_t)48 * NEUR;

    fx4 acc[4];
#pragma unroll
    for (int tb = 0; tb < 4; ++tb) acc[tb] = (fx4){0.f, 0.f, 0.f, 0.f};

    float4 st[8];                          // one tile of stage data in regs

    // 2 rows x 512B contiguous per instruction; 8 instrs = 16 rows x 512B
#define SLOAD(s)                                                              \
    { _Pragma("unroll") for (int it = 0; it < 8; ++it)                        \
        st[it] = *(const float4*)(wst + (size_t)(it * 2) * NEUR + (s) * 128); }

    // swizzled LDS write: byte = r*256 + ((sc*8) ^ ((r&7)<<4))  [8B granule]
#define SWRITE(b)                                                             \
    { _Pragma("unroll") for (int it = 0; it < 8; ++it) {                      \
        const int r_ = wrow0 + it * 2 + sr;                                   \
        const us4 o_ = {f2b(st[it].x), f2b(st[it].y),                         \
                        f2b(st[it].z), f2b(st[it].w)};                        \
        *(us4*)(&smem[b][r_ * 256 + ((sc * 8) ^ ((r_ & 7) << 4))]) = o_; } }

    // 4 MFMA K-steps per tile; B-fragment via swizzled ds_read_b128
#define CTILE(s, b)                                                           \
    { _Pragma("unroll") for (int kk = 0; kk < 4; ++kk) {                      \
        const int e_ = (s) * 128 + kk * 32;                                   \
        const bs8 a0 = *(const bs8*)(xq0 + e_);                               \
        const bs8 a1 = *(const bs8*)(xq1 + e_);                               \
        const bs8 a2 = *(const bs8*)(xq2 + e_);                               \
        const bs8 a3 = *(const bs8*)(xq3 + e_);                               \
        const bs8 bb = *(const bs8*)(&smem[b][(wrow0 + lrow) * 256 +          \
                          ((kk * 64 + lgrp * 16) ^ ((lrow & 7) << 4))]);      \
        acc[0] = __builtin_amdgcn_mfma_f32_16x16x32_bf16(a0, bb, acc[0], 0, 0, 0); \
        acc[1] = __builtin_amdgcn_mfma_f32_16x16x32_bf16(a1, bb, acc[1], 0, 0, 0); \
        acc[2] = __builtin_amdgcn_mfma_f32_16x16x32_bf16(a2, bb, acc[2], 0, 0, 0); \
        acc[3] = __builtin_amdgcn_mfma_f32_16x16x32_bf16(a3, bb, acc[3], 0, 0, 0); } }

    // per-wave software pipeline; LDS is wave-private -> NO barriers anywhere
    SLOAD(0); SWRITE(0);
#pragma unroll
    for (int s = 0; s < NTILE; ++s) {
        if (s + 1 < NTILE) SLOAD(s + 1);   // next tile's HBM loads in flight
        CTILE(s, s & 1);                   // compute current tile
        if (s + 1 < NTILE) SWRITE((s + 1) & 1);
    }
#undef SLOAD
#undef SWRITE
#undef CTILE

    // epilogue: C/D layout col = lane&15 (-> j), row = (lane>>4)*4 + reg (-> t)
#pragma unroll
    for (int tb = 0; tb < 4; ++tb)
#pragma unroll
        for (int i = 0; i < 4; ++i) {
            const int t = tb * 16 + lgrp * 4 + i;
            if (t < TSTEPS)
                P[((size_t)ks * TSTEPS + t) * NEUR + j0 + wrow0 + lrow] =
                    f2b(acc[tb][i]);
        }
}

// ---------------- K2: fused partial-reduce + speculative LIF scan ----------------
__global__ __launch_bounds__(128)
void scan_fused(const unsigned short* __restrict__ P, float* __restrict__ FF,
                float* __restrict__ out, int* __restrict__ flag)
{
    const int j = blockIdx.x * 128 + threadIdx.x;   // one neuron per thread
    float ff[TSTEPS];
#pragma unroll
    for (int t = 0; t < TSTEPS; ++t) ff[t] = 0.f;
#pragma unroll
    for (int ksp = 0; ksp < KSPLIT; ++ksp)
#pragma unroll
        for (int t = 0; t < TSTEPS; ++t)
            ff[t] += b2f(P[((size_t)ksp * TSTEPS + t) * NEUR + j]);

    float v = -70.f, cur = 0.f;
    bool any = false;
#pragma unroll
    for (int t = 0; t < TSTEPS; ++t) {
        FF[(size_t)t * NEUR + j] = ff[t];           // for the fallback path
        const float vd = v + 5.0e-5f * ((-70.f - v) + cur);
        const float id = cur - 1.0e-4f * cur;
        const bool sp = vd > -55.f;
        any |= sp;
        v = sp ? -70.f : vd;
        cur = id + ff[t];                           // no recurrence (speculation)
        out[(size_t)t * NEUR + j] = sp ? 1.f : 0.f;
    }
    if (any) atomicAdd(flag, 1);
}

// ---------------- K3: exact event-driven fallback (only if spikes occurred) ----------------
__global__ __launch_bounds__(1024)
void lif_fallback(const float* __restrict__ FF, const float* __restrict__ wrec,
                  float* __restrict__ out, const int* __restrict__ flag)
{
    if (*flag == 0) return;   // speculation was self-consistent -> out is exact

    const int tid = threadIdx.x;
    __shared__ unsigned short list[2][NEUR];
    __shared__ int cnt[2];

    float v[8], cur[8];
#pragma unroll
    for (int n = 0; n < 8; ++n) { v[n] = -70.0f; cur[n] = 0.0f; }
    if (tid == 0) { cnt[0] = 0; cnt[1] = 0; }

    for (int t = 0; t < TSTEPS; ++t) {
        const int rb = t & 1, wb = rb ^ 1;
        __syncthreads();
        if (tid == 0) cnt[wb] = 0;
        __syncthreads();

        float rec[8];
#pragma unroll
        for (int n = 0; n < 8; ++n) rec[n] = 0.0f;
        const int c = cnt[rb];
        for (int s = 0; s < c; ++s) {
            const int k = list[rb][s];
#pragma unroll
            for (int n = 0; n < 8; ++n)
                rec[n] += wrec[(size_t)(tid + n * 1024) * NEUR + k];
        }

#pragma unroll
        for (int n = 0; n < 8; ++n) {
            const float ff = FF[(size_t)t * NEUR + tid + n * 1024];
            const float vd = v[n] + 5.0e-5f * ((-70.0f - v[n]) + cur[n]);
            const float id = cur[n] - 1.0e-4f * cur[n];
            const bool  sp = vd > -55.0f;
            v[n]   = sp ? -70.0f : vd;
            cur[n] = id + ff + rec[n];
            out[(size_t)t * NEUR + tid + n * 1024] = sp ? 1.0f : 0.0f;
            if (sp) {
                const int pos = atomicAdd(&cnt[wb], 1);
                list[wb][pos] = (unsigned short)(tid + n * 1024);
            }
        }
    }
}

extern "C" void kernel_launch(void* const* d_in, const int* in_sizes, int n_in,
                              void* d_out, int out_size, void* d_ws, size_t ws_size,
                              hipStream_t stream) {
    const float* x     = (const float*)d_in[0];   // [50][8192]
    const float* w_in  = (const float*)d_in[1];   // [8192][8192]
    const float* w_rec = (const float*)d_in[2];   // [8192][8192]
    float* out = (float*)d_out;

    // ws layout (16B-aligned):
    //   FF  f32  [50][8192]          1,638,400 B  @ 0
    //   xb  bf16 [64][8192]          1,048,576 B  @ 1,638,400
    //   P   bf16 [8][50][8192]       6,553,600 B  @ 2,686,976
    //   flag int                             4 B  @ 9,240,576
    float* FF          = (float*)d_ws;
    unsigned short* xb = (unsigned short*)((char*)d_ws + 1638400);
    unsigned short* P  = (unsigned short*)((char*)d_ws + 2686976);
    int* flag          = (int*)((char*)d_ws + 9240576);

    prep        <<<dim3(TPAD * NEUR / 8 / 256), dim3(256),  0, stream>>>(x, xb, flag);
    ff_gemm_mfma<<<dim3(128 * KSPLIT),          dim3(256),  0, stream>>>(w_in, xb, P);
    scan_fused  <<<dim3(NEUR / 128),            dim3(128),  0, stream>>>(P, FF, out, flag);
    lif_fallback<<<dim3(1),                     dim3(1024), 0, stream>>>(FF, w_rec, out, flag);
}